// Round 6
// baseline (666.506 us; speedup 1.0000x reference)
//
#include <hip/hip_runtime.h>
#include <hip/hip_bf16.h>

typedef unsigned short u16;
typedef unsigned int u32;
typedef short bf16x8 __attribute__((ext_vector_type(8)));
typedef float floatx4 __attribute__((ext_vector_type(4)));

#define CTX 2048
#define HEADSZ 64
#define NHEAD 16
#define DMODEL 1024
#define DFF 4096
#define MROWS 8192  // B*T
#define C_SCALE 0.18033688011112042f  // 0.125 * log2(e)

__device__ __forceinline__ u16 f2b(float f) {
  union { float f; u32 i; } x; x.f = f;
  u32 i = x.i;
  return (u16)((i + 0x7fffu + ((i >> 16) & 1u)) >> 16);  // RNE
}
__device__ __forceinline__ u32 pack2(float a, float b) {
  return (u32)f2b(a) | ((u32)f2b(b) << 16);
}
__device__ __forceinline__ floatx4 fmax4(floatx4 a, floatx4 b) {
  floatx4 r;
  r[0] = fmaxf(a[0], b[0]); r[1] = fmaxf(a[1], b[1]);
  r[2] = fmaxf(a[2], b[2]); r[3] = fmaxf(a[3], b[3]);
  return r;
}

__device__ __forceinline__ void gl2lds16(const u16* g, u16* l) {
  __builtin_amdgcn_global_load_lds(
      (const __attribute__((address_space(1))) void*)g,
      (__attribute__((address_space(3))) void*)l, 16, 0, 0);
}

// ---------------- elementwise fp32 -> bf16 (4 elems/thread) -------------------
__global__ __launch_bounds__(256) void cvt_f32_bf16(const float* __restrict__ in,
                                                    u16* __restrict__ out) {
  int i = (blockIdx.x * 256 + threadIdx.x) * 4;
  float4 v = *(const float4*)(in + i);
  *(uint2*)(out + i) = make_uint2(pack2(v.x, v.y), pack2(v.z, v.w));
}

// ------------- batched transpose: out_bf16[z][c][r] = in_f32[z][r][c] ---------
__global__ void transpose_f32_bf16(const float* __restrict__ in, u16* __restrict__ out,
                                   int R, int C, long ibs, long obs) {
  __shared__ u16 tile[32][33];
  const float* ip = in + (size_t)blockIdx.z * ibs;
  u16* op = out + (size_t)blockIdx.z * obs;
  int c0 = blockIdx.x * 32, r0 = blockIdx.y * 32;
  int tx = threadIdx.x, ty = threadIdx.y;
#pragma unroll
  for (int i = 0; i < 32; i += 8)
    tile[ty + i][tx] = f2b(ip[(size_t)(r0 + ty + i) * C + (c0 + tx)]);
  __syncthreads();
#pragma unroll
  for (int i = 0; i < 32; i += 8)
    op[(size_t)(c0 + ty + i) * R + (r0 + tx)] = tile[tx][ty + i];
}

// ------ combined per-head transpose of Wq/Wk/Wv [16][1024][64] fp32
//        -> Wqkvt rows sec*1024 + head*64 .. ( [64][1024] per head, bf16 )
__global__ void transpose_qkv(const float* __restrict__ Wq, const float* __restrict__ Wk,
                              const float* __restrict__ Wv, u16* __restrict__ out) {
  __shared__ u16 tile[32][33];
  int z = blockIdx.z;               // 0..47
  int sec = z >> 4, hh = z & 15;
  const float* ip = (sec == 0 ? Wq : sec == 1 ? Wk : Wv) + (size_t)hh * 65536;
  u16* op = out + (size_t)(sec * 16 + hh) * 65536;
  int c0 = blockIdx.x * 32, r0 = blockIdx.y * 32;
  int tx = threadIdx.x, ty = threadIdx.y;
#pragma unroll
  for (int i = 0; i < 32; i += 8)
    tile[ty + i][tx] = f2b(ip[(size_t)(r0 + ty + i) * 64 + (c0 + tx)]);
  __syncthreads();
#pragma unroll
  for (int i = 0; i < 32; i += 8)
    op[(size_t)(c0 + ty + i) * 1024 + (r0 + tx)] = tile[tx][ty + i];
}

// ------------- bf16 transpose: v [BH][2048][64] -> vt [BH][64][2048] ----------
__global__ void transpose_v_bf16(const u16* __restrict__ in, u16* __restrict__ out) {
  __shared__ u16 tile[32][33];
  const u16* ip = in + (size_t)blockIdx.z * (CTX * 64);
  u16* op = out + (size_t)blockIdx.z * (CTX * 64);
  int c0 = blockIdx.x * 32, r0 = blockIdx.y * 32;
  int tx = threadIdx.x, ty = threadIdx.y;
#pragma unroll
  for (int i = 0; i < 32; i += 8)
    tile[ty + i][tx] = ip[(size_t)(r0 + ty + i) * 64 + (c0 + tx)];
  __syncthreads();
#pragma unroll
  for (int i = 0; i < 32; i += 8)
    op[(size_t)(c0 + ty + i) * CTX + (r0 + tx)] = tile[tx][ty + i];
}

// ---------------- GEMM: C[m][n] = sum_k A[m][k] * Bt[n][k]  (+epilogue) --------
// 128x128 tile, BK=32, TRIPLE-buffered LDS, ONE raw barrier per stage with
// s_waitcnt vmcnt(4): the 4 prefetch DMAs for stage t+1 stay in flight across
// the barrier (AITER-style K-loop; __syncthreads would drain vmcnt(0)).
// Triple-buffer => DMA target buffer was last read two barriers ago (safe).
// 1D grid, XCD swizzle: xcd=id%8 owns N-band of NB 128-wide tiles.
// MODE 0: scatter bf16 to q/k/v [B,H,T,64] (o0,o1,o2)
// MODE 1: bf16 o0[m*N+n] = acc + bias[n]
// MODE 2: f32  o0[m*N+n] = relu(acc + bias[n])
template <int MODE>
__global__ __launch_bounds__(256) void gemm_bt(
    const u16* __restrict__ A, const u16* __restrict__ Bt,
    const float* __restrict__ bias,
    void* __restrict__ o0v, void* __restrict__ o1v, void* __restrict__ o2v,
    int N, int K, int NB) {
  __shared__ __align__(16) u16 As[3][128 * 32];  // 8 KB per buf
  __shared__ __align__(16) u16 Bs[3][128 * 32];
  const int tid = threadIdx.x;
  const int wave = tid >> 6, lane = tid & 63;
  const int quad = lane >> 4, l15 = lane & 15;
  const int wm = wave >> 1, wn = wave & 1;

  const int id = blockIdx.x;
  const int xcd = id & 7, local = id >> 3;
  const int mt = local / NB;
  const int nt = xcd * NB + (local - mt * NB);
  const int blockM = mt * 128, blockN = nt * 128;

  // staging: 512 chunks of 8 u16 per buf; chunk c = kc*128+row at LDS off c*8.
  // thread tid loads chunks tid and tid+256 (kc0 and kc0+2).
  const u16* ga = A + (size_t)(blockM + (tid & 127)) * K + (tid >> 7) * 8;
  const u16* gb = Bt + (size_t)(blockN + (tid & 127)) * K + (tid >> 7) * 8;

  floatx4 acc[4][4];
#pragma unroll
  for (int i = 0; i < 4; i++)
#pragma unroll
    for (int j = 0; j < 4; j++) acc[i][j] = (floatx4){0.f, 0.f, 0.f, 0.f};

  const int nk = K >> 5;
  // prologue: stage 0 -> buf 0
  gl2lds16(ga, &As[0][tid * 8]);
  gl2lds16(ga + 16, &As[0][(tid + 256) * 8]);
  gl2lds16(gb, &Bs[0][tid * 8]);
  gl2lds16(gb + 16, &Bs[0][(tid + 256) * 8]);

  int cur = 0;
  for (int kt = 0; kt < nk; kt++) {
    if (kt + 1 < nk) {
      int nxt = (cur == 2) ? 0 : cur + 1;
      const u16* ga2 = ga + 32;
      const u16* gb2 = gb + 32;
      gl2lds16(ga2, &As[nxt][tid * 8]);
      gl2lds16(ga2 + 16, &As[nxt][(tid + 256) * 8]);
      gl2lds16(gb2, &Bs[nxt][tid * 8]);
      gl2lds16(gb2 + 16, &Bs[nxt][(tid + 256) * 8]);
      ga += 32; gb += 32;
      asm volatile("s_waitcnt vmcnt(4)\n\ts_barrier" ::: "memory");
    } else {
      asm volatile("s_waitcnt vmcnt(0)\n\ts_barrier" ::: "memory");
    }
    const bf16x8* Ac = (const bf16x8*)As[cur];
    const bf16x8* Bc = (const bf16x8*)Bs[cur];
    bf16x8 af[4], bfr[4];
#pragma unroll
    for (int i = 0; i < 4; i++) af[i] = Ac[quad * 128 + wm * 64 + i * 16 + l15];
#pragma unroll
    for (int j = 0; j < 4; j++) bfr[j] = Bc[quad * 128 + wn * 64 + j * 16 + l15];
#pragma unroll
    for (int i = 0; i < 4; i++)
#pragma unroll
      for (int j = 0; j < 4; j++)
        acc[i][j] = __builtin_amdgcn_mfma_f32_16x16x32_bf16(af[i], bfr[j], acc[i][j], 0, 0, 0);
    cur = (cur == 2) ? 0 : cur + 1;
  }

  const int m0 = blockM + wm * 64 + quad * 4;
  const int n0 = blockN + wn * 64 + l15;
  if (MODE == 0) {
    u16* o0 = (u16*)o0v; u16* o1 = (u16*)o1v; u16* o2 = (u16*)o2v;
#pragma unroll
    for (int j = 0; j < 4; j++) {
      int n = n0 + j * 16;
      int sec = n >> 10, hh = (n >> 6) & 15, d = n & 63;
      u16* dst = (sec == 0) ? o0 : (sec == 1) ? o1 : o2;
#pragma unroll
      for (int i = 0; i < 4; i++)
#pragma unroll
        for (int r = 0; r < 4; r++) {
          int m = m0 + i * 16 + r;
          int b = m >> 11, t = m & 2047;
          dst[((size_t)((b * 16 + hh) * 2048 + t)) * 64 + d] = f2b(acc[i][j][r]);
        }
    }
  } else if (MODE == 1) {
    u16* o0 = (u16*)o0v;
#pragma unroll
    for (int j = 0; j < 4; j++) {
      int n = n0 + j * 16;
      float bv = bias[n];
#pragma unroll
      for (int i = 0; i < 4; i++)
#pragma unroll
        for (int r = 0; r < 4; r++) {
          int m = m0 + i * 16 + r;
          o0[(size_t)m * N + n] = f2b(acc[i][j][r] + bv);
        }
    }
  } else {
    float* o0 = (float*)o0v;
#pragma unroll
    for (int j = 0; j < 4; j++) {
      int n = n0 + j * 16;
      float bv = bias[n];
#pragma unroll
      for (int i = 0; i < 4; i++)
#pragma unroll
        for (int r = 0; r < 4; r++) {
          int m = m0 + i * 16 + r;
          float v = acc[i][j][r] + bv;
          o0[(size_t)m * N + n] = v > 0.f ? v : 0.f;
        }
    }
  }
}

// ---------------- MFMA causal flash attention, LDS-staged, balanced -----------
__global__ __launch_bounds__(256) void attn_mfma(
    const u16* __restrict__ Q, const u16* __restrict__ K,
    const u16* __restrict__ Vt, u16* __restrict__ out) {
  __shared__ __align__(16) u16 Kbuf[2][4096];
  __shared__ __align__(16) u16 Vbuf[2][4096];
  __shared__ __align__(16) u16 Plds[4][32][72];
  const int tid = threadIdx.x;
  const int wave = tid >> 6, lane = tid & 63;
  const int quad = lane >> 4, l15 = lane & 15;
  const int sx = l15 & 7;
  const int bh = blockIdx.y;
  const int u = blockIdx.x;
  const size_t qkb = (size_t)bh * CTX * 64;
  const size_t vb = (size_t)bh * 64 * CTX;

  const int ch0 = wave * 64 + lane;
  const int ch1 = 256 + ch0;
  const int r0 = ch0 >> 3, s0 = (ch0 & 7) ^ (r0 & 7);
  const int r1 = ch1 >> 3, s1 = (ch1 & 7) ^ (r1 & 7);
  const u16* kg0 = K + qkb + r0 * 64 + s0 * 8;
  const u16* kg1 = K + qkb + r1 * 64 + s1 * 8;
  const u16* vg0 = Vt + vb + (size_t)r0 * CTX + s0 * 8;
  const u16* vg1 = Vt + vb + (size_t)r1 * CTX + s1 * 8;

#pragma unroll 1
  for (int pass = 0; pass < 2; pass++) {
    const int j = pass ? (15 - u) : u;
    const int qbase = j * 128 + wave * 32;
    const int NST = 2 * j + 2;
    const int nstw = 2 * j + (wave >> 1) + 1;

    bf16x8 qf[2][2];
#pragma unroll
    for (int mt = 0; mt < 2; mt++)
#pragma unroll
      for (int kc = 0; kc < 2; kc++)
        qf[mt][kc] = *(const bf16x8*)(Q + qkb + (size_t)(qbase + mt * 16 + l15) * 64 + kc * 32 + quad * 8);

    floatx4 o[2][4];
#pragma unroll
    for (int mt = 0; mt < 2; mt++)
#pragma unroll
      for (int dt = 0; dt < 4; dt++) o[mt][dt] = (floatx4){0.f, 0.f, 0.f, 0.f};
    float mrow[2] = {-1e30f, -1e30f};
    float lrow[2] = {0.f, 0.f};

    __syncthreads();
    gl2lds16(kg0, &Kbuf[0][wave * 512]);
    gl2lds16(kg1, &Kbuf[0][2048 + wave * 512]);
    gl2lds16(vg0, &Vbuf[0][wave * 512]);
    gl2lds16(vg1, &Vbuf[0][2048 + wave * 512]);

#pragma unroll 1
    for (int st = 0; st < NST; st++) {
      __syncthreads();
      if (st + 1 < NST) {
        const int sb = (st + 1) * 64;
        const int b = (st + 1) & 1;
        gl2lds16(kg0 + sb * 64, &Kbuf[b][wave * 512]);
        gl2lds16(kg1 + sb * 64, &Kbuf[b][2048 + wave * 512]);
        gl2lds16(vg0 + sb, &Vbuf[b][wave * 512]);
        gl2lds16(vg1 + sb, &Vbuf[b][2048 + wave * 512]);
      }
      if (st >= nstw) continue;
      const int sbase = st * 64;
      const u16* kb = Kbuf[st & 1];
      const u16* vv = Vbuf[st & 1];

      floatx4 stf[2][4];
#pragma unroll
      for (int sc = 0; sc < 4; sc++) {
        const bf16x8* kr = (const bf16x8*)(kb + (sc * 16 + l15) * 64);
        bf16x8 k0 = kr[quad ^ sx];
        bf16x8 k1 = kr[(4 + quad) ^ sx];
#pragma unroll
        for (int mt = 0; mt < 2; mt++) {
          floatx4 z = (floatx4){0.f, 0.f, 0.f, 0.f};
          z = __builtin_amdgcn_mfma_f32_16x16x32_bf16(k0, qf[mt][0], z, 0, 0, 0);
          stf[mt][sc] = __builtin_amdgcn_mfma_f32_16x16x32_bf16(k1, qf[mt][1], z, 0, 0, 0);
        }
      }
      if (st == nstw - 1) {
#pragma unroll
        for (int mt = 0; mt < 2; mt++) {
          int qq = qbase + mt * 16 + l15;
#pragma unroll
          for (int sc = 0; sc < 4; sc++)
#pragma unroll
            for (int r = 0; r < 4; r++) {
              int s = sbase + sc * 16 + quad * 4 + r;
              if (s > qq) stf[mt][sc][r] = -1e30f;
            }
        }
      }
#pragma unroll
      for (int mt = 0; mt < 2; mt++) {
        floatx4 m4 = fmax4(fmax4(stf[mt][0], stf[mt][1]), fmax4(stf[mt][2], stf[mt][3]));
        float tm = fmaxf(fmaxf(m4[0], m4[1]), fmaxf(m4[2], m4[3]));
        tm = fmaxf(tm, __shfl_xor(tm, 16));
        tm = fmaxf(tm, __shfl_xor(tm, 32));
        float mnew = fmaxf(mrow[mt], tm);
        float alpha = exp2f((mrow[mt] - mnew) * C_SCALE);
        float mc = mnew * C_SCALE;
        mrow[mt] = mnew;
        float lsum = 0.f;
#pragma unroll
        for (int sc = 0; sc < 4; sc++) {
          floatx4 s4 = stf[mt][sc];
          float p0 = exp2f(s4[0] * C_SCALE - mc);
          float p1 = exp2f(s4[1] * C_SCALE - mc);
          float p2 = exp2f(s4[2] * C_SCALE - mc);
          float p3 = exp2f(s4[3] * C_SCALE - mc);
          lsum += (p0 + p1) + (p2 + p3);
          *(uint2*)&Plds[wave][mt * 16 + l15][sc * 16 + quad * 4] =
              make_uint2(pack2(p0, p1), pack2(p2, p3));
        }
        lrow[mt] = lrow[mt] * alpha + lsum;
#pragma unroll
        for (int dt = 0; dt < 4; dt++) o[mt][dt] *= alpha;
      }
      asm volatile("s_waitcnt lgkmcnt(0)" ::: "memory");
#pragma unroll
      for (int sc2 = 0; sc2 < 2; sc2++) {
        bf16x8 pf[2];
#pragma unroll
        for (int mt = 0; mt < 2; mt++)
          pf[mt] = *(const bf16x8*)&Plds[wave][mt * 16 + l15][sc2 * 32 + quad * 8];
#pragma unroll
        for (int dt = 0; dt < 4; dt++) {
          const bf16x8* vr = (const bf16x8*)(vv + (dt * 16 + l15) * 64);
          bf16x8 vf = vr[(sc2 * 4 + quad) ^ sx];
#pragma unroll
          for (int mt = 0; mt < 2; mt++)
            o[mt][dt] = __builtin_amdgcn_mfma_f32_16x16x32_bf16(vf, pf[mt], o[mt][dt], 0, 0, 0);
        }
      }
    }

#pragma unroll
    for (int mt = 0; mt < 2; mt++) {
      float l = lrow[mt];
      l += __shfl_xor(l, 16);
      l += __shfl_xor(l, 32);
      float inv = 1.0f / l;
      int row = (bh >> 4) * CTX + qbase + mt * 16 + l15;
      u16* orow = out + (size_t)row * DMODEL + (bh & 15) * 64;
#pragma unroll
      for (int dt = 0; dt < 4; dt++) {
        floatx4 v = o[mt][dt];
        *(u32*)(orow + dt * 16 + quad * 4) = pack2(v[0] * inv, v[1] * inv);
        *(u32*)(orow + dt * 16 + quad * 4 + 2) = pack2(v[2] * inv, v[3] * inv);
      }
    }
  }
}

extern "C" void kernel_launch(void* const* d_in, const int* in_sizes, int n_in,
                              void* d_out, int out_size, void* d_ws, size_t ws_size,
                              hipStream_t stream) {
  const float* x  = (const float*)d_in[0];
  const float* Wq = (const float*)d_in[1];
  const float* Wk = (const float*)d_in[2];
  const float* Wv = (const float*)d_in[3];
  const float* W1 = (const float*)d_in[4];
  const float* b1 = (const float*)d_in[5];
  const float* W2 = (const float*)d_in[6];
  const float* b2 = (const float*)d_in[7];
  float* out = (float*)d_out;

  u16* ws    = (u16*)d_ws;
  u16* W1t   = ws;                             // [4096][1024]
  u16* W2t   = W1t + (size_t)4096 * 1024;      // [1024][4096]
  u16* att   = W2t + (size_t)4096 * 1024;      // [B*T][1024]  (also v_tmp)
  u16* xb    = att + (size_t)MROWS * 1024;     // [B*T][1024]
  u16* Wqkvt = xb + (size_t)MROWS * 1024;      // [3072][1024]
  u16* q     = Wqkvt + (size_t)3072 * 1024;    // [B*H][T][64]
  u16* k     = q + (size_t)MROWS * 1024;       // [B*H][T][64]
  u16* vt    = k + (size_t)MROWS * 1024;       // [B*H][64][T]
  u16* v_tmp = att;                            // [B*H][T][64]
  u16* h     = xb;                             // [B*T][4096] overlaps xb..vt

  cvt_f32_bf16<<<MROWS * 1024 / 1024, 256, 0, stream>>>(x, xb);

  dim3 tb(32, 8);
  transpose_qkv<<<dim3(2, 32, 48), tb, 0, stream>>>(Wq, Wk, Wv, Wqkvt);
  transpose_f32_bf16<<<dim3(128, 32, 1), tb, 0, stream>>>(W1, W1t, 1024, 4096, 0, 0);
  transpose_f32_bf16<<<dim3(32, 128, 1), tb, 0, stream>>>(W2, W2t, 4096, 1024, 0, 0);

  // QKV projection: [8192][1024] x [3072][1024]^T -> q/k/v (coalesced scatter)
  gemm_bt<0><<<1536, 256, 0, stream>>>(xb, Wqkvt, nullptr, q, k, v_tmp, 3072, 1024, 3);
  // v [BH][T][64] -> vt [BH][64][T]
  transpose_v_bf16<<<dim3(2, 64, 64), tb, 0, stream>>>(v_tmp, vt);
  // MFMA causal flash attention -> att [B*T][1024]
  attn_mfma<<<dim3(8, 64), 256, 0, stream>>>(q, k, vt, att);
  // FFN1: att @ W1 + b1 -> h (bf16)
  gemm_bt<1><<<2048, 256, 0, stream>>>(att, W1t, b1, h, nullptr, nullptr, 4096, 1024, 4);
  // FFN2: relu(h @ W2 + b2) -> out (fp32)
  gemm_bt<2><<<512, 256, 0, stream>>>(h, W2t, b2, out, nullptr, nullptr, 1024, 4096, 1);
}

// Round 7
// 628.770 us; speedup vs baseline: 1.0600x; 1.0600x over previous
//
#include <hip/hip_runtime.h>
#include <hip/hip_bf16.h>

typedef unsigned short u16;
typedef unsigned int u32;
typedef short bf16x8 __attribute__((ext_vector_type(8)));
typedef float floatx4 __attribute__((ext_vector_type(4)));

#define CTX 2048
#define HEADSZ 64
#define NHEAD 16
#define DMODEL 1024
#define DFF 4096
#define MROWS 8192  // B*T
#define C_SCALE 0.18033688011112042f  // 0.125 * log2(e)

__device__ __forceinline__ u16 f2b(float f) {
  union { float f; u32 i; } x; x.f = f;
  u32 i = x.i;
  return (u16)((i + 0x7fffu + ((i >> 16) & 1u)) >> 16);  // RNE
}
__device__ __forceinline__ u32 pack2(float a, float b) {
  return (u32)f2b(a) | ((u32)f2b(b) << 16);
}
__device__ __forceinline__ floatx4 fmax4(floatx4 a, floatx4 b) {
  floatx4 r;
  r[0] = fmaxf(a[0], b[0]); r[1] = fmaxf(a[1], b[1]);
  r[2] = fmaxf(a[2], b[2]); r[3] = fmaxf(a[3], b[3]);
  return r;
}

__device__ __forceinline__ void gl2lds16(const u16* g, u16* l) {
  __builtin_amdgcn_global_load_lds(
      (const __attribute__((address_space(1))) void*)g,
      (__attribute__((address_space(3))) void*)l, 16, 0, 0);
}

// ---------------- elementwise fp32 -> bf16 (4 elems/thread) -------------------
__global__ __launch_bounds__(256) void cvt_f32_bf16(const float* __restrict__ in,
                                                    u16* __restrict__ out) {
  int i = (blockIdx.x * 256 + threadIdx.x) * 4;
  float4 v = *(const float4*)(in + i);
  *(uint2*)(out + i) = make_uint2(pack2(v.x, v.y), pack2(v.z, v.w));
}

// ------------- batched transpose: out_bf16[z][c][r] = in_f32[z][r][c] ---------
__global__ void transpose_f32_bf16(const float* __restrict__ in, u16* __restrict__ out,
                                   int R, int C, long ibs, long obs) {
  __shared__ u16 tile[32][33];
  const float* ip = in + (size_t)blockIdx.z * ibs;
  u16* op = out + (size_t)blockIdx.z * obs;
  int c0 = blockIdx.x * 32, r0 = blockIdx.y * 32;
  int tx = threadIdx.x, ty = threadIdx.y;
#pragma unroll
  for (int i = 0; i < 32; i += 8)
    tile[ty + i][tx] = f2b(ip[(size_t)(r0 + ty + i) * C + (c0 + tx)]);
  __syncthreads();
#pragma unroll
  for (int i = 0; i < 32; i += 8)
    op[(size_t)(c0 + ty + i) * R + (r0 + tx)] = tile[tx][ty + i];
}

// ------ combined per-head transpose of Wq/Wk/Wv [16][1024][64] fp32
//        -> Wqkvt rows sec*1024 + head*64 .. ( [64][1024] per head, bf16 )
__global__ void transpose_qkv(const float* __restrict__ Wq, const float* __restrict__ Wk,
                              const float* __restrict__ Wv, u16* __restrict__ out) {
  __shared__ u16 tile[32][33];
  int z = blockIdx.z;               // 0..47
  int sec = z >> 4, hh = z & 15;
  const float* ip = (sec == 0 ? Wq : sec == 1 ? Wk : Wv) + (size_t)hh * 65536;
  u16* op = out + (size_t)(sec * 16 + hh) * 65536;
  int c0 = blockIdx.x * 32, r0 = blockIdx.y * 32;
  int tx = threadIdx.x, ty = threadIdx.y;
#pragma unroll
  for (int i = 0; i < 32; i += 8)
    tile[ty + i][tx] = f2b(ip[(size_t)(r0 + ty + i) * 64 + (c0 + tx)]);
  __syncthreads();
#pragma unroll
  for (int i = 0; i < 32; i += 8)
    op[(size_t)(c0 + ty + i) * 1024 + (r0 + tx)] = tile[tx][ty + i];
}

// ------------- bf16 transpose: v [BH][2048][64] -> vt [BH][64][2048] ----------
__global__ void transpose_v_bf16(const u16* __restrict__ in, u16* __restrict__ out) {
  __shared__ u16 tile[32][33];
  const u16* ip = in + (size_t)blockIdx.z * (CTX * 64);
  u16* op = out + (size_t)blockIdx.z * (CTX * 64);
  int c0 = blockIdx.x * 32, r0 = blockIdx.y * 32;
  int tx = threadIdx.x, ty = threadIdx.y;
#pragma unroll
  for (int i = 0; i < 32; i += 8)
    tile[ty + i][tx] = ip[(size_t)(r0 + ty + i) * 64 + (c0 + tx)];
  __syncthreads();
#pragma unroll
  for (int i = 0; i < 32; i += 8)
    op[(size_t)(c0 + ty + i) * CTX + (r0 + tx)] = tile[tx][ty + i];
}

// ---------------- GEMM: C[m][n] = sum_k A[m][k] * Bt[n][k]  (+epilogue) --------
// 128x128 tile, BK=32, triple-buffered LDS, DEPTH-2 prefetch:
//   iter t: s_waitcnt vmcnt(4) (drain stage t's 4 DMAs; t+1,t+2 stay in flight)
//           s_barrier
//           issue DMA(t+2) into buf[(t+2)%3]  (safe: last read in compute(t-1),
//                                              finished by all waves pre-barrier)
//           compute stage t
// Stage data has ~2 stages of compute (~600 cyc) to land -> covers L2-miss/L3.
// 1D grid, XCD swizzle: xcd=id%8 owns N-band of NB 128-wide tiles.
// MODE 0: scatter bf16 to q/k/v [B,H,T,64] (o0,o1,o2)
// MODE 1: bf16 o0[m*N+n] = acc + bias[n]
// MODE 2: f32  o0[m*N+n] = relu(acc + bias[n])
template <int MODE>
__global__ __launch_bounds__(256) void gemm_bt(
    const u16* __restrict__ A, const u16* __restrict__ Bt,
    const float* __restrict__ bias,
    void* __restrict__ o0v, void* __restrict__ o1v, void* __restrict__ o2v,
    int N, int K, int NB) {
  __shared__ __align__(16) u16 As[3][128 * 32];  // 8 KB per buf
  __shared__ __align__(16) u16 Bs[3][128 * 32];
  const int tid = threadIdx.x;
  const int wave = tid >> 6, lane = tid & 63;
  const int quad = lane >> 4, l15 = lane & 15;
  const int wm = wave >> 1, wn = wave & 1;

  const int id = blockIdx.x;
  const int xcd = id & 7, local = id >> 3;
  const int mt = local / NB;
  const int nt = xcd * NB + (local - mt * NB);
  const int blockM = mt * 128, blockN = nt * 128;

  // staging: 512 chunks of 8 u16 per buf; chunk c = kc*128+row at LDS off c*8.
  const u16* ga = A + (size_t)(blockM + (tid & 127)) * K + (tid >> 7) * 8;
  const u16* gb = Bt + (size_t)(blockN + (tid & 127)) * K + (tid >> 7) * 8;

  floatx4 acc[4][4];
#pragma unroll
  for (int i = 0; i < 4; i++)
#pragma unroll
    for (int j = 0; j < 4; j++) acc[i][j] = (floatx4){0.f, 0.f, 0.f, 0.f};

  const int nk = K >> 5;
  // prologue: stages 0,1 -> bufs 0,1
  gl2lds16(ga, &As[0][tid * 8]);
  gl2lds16(ga + 16, &As[0][(tid + 256) * 8]);
  gl2lds16(gb, &Bs[0][tid * 8]);
  gl2lds16(gb + 16, &Bs[0][(tid + 256) * 8]);
  gl2lds16(ga + 32, &As[1][tid * 8]);
  gl2lds16(ga + 48, &As[1][(tid + 256) * 8]);
  gl2lds16(gb + 32, &Bs[1][tid * 8]);
  gl2lds16(gb + 48, &Bs[1][(tid + 256) * 8]);
  ga += 64; gb += 64;  // next issue point = stage 2

  int cur = 0;
  for (int kt = 0; kt < nk; kt++) {
    if (kt + 1 < nk)
      asm volatile("s_waitcnt vmcnt(4)\n\ts_barrier" ::: "memory");
    else
      asm volatile("s_waitcnt vmcnt(0)\n\ts_barrier" ::: "memory");
    if (kt + 2 < nk) {
      int nxt = cur + 2; if (nxt >= 3) nxt -= 3;
      gl2lds16(ga, &As[nxt][tid * 8]);
      gl2lds16(ga + 16, &As[nxt][(tid + 256) * 8]);
      gl2lds16(gb, &Bs[nxt][tid * 8]);
      gl2lds16(gb + 16, &Bs[nxt][(tid + 256) * 8]);
      ga += 32; gb += 32;
    }
    const bf16x8* Ac = (const bf16x8*)As[cur];
    const bf16x8* Bc = (const bf16x8*)Bs[cur];
    bf16x8 af[4], bfr[4];
#pragma unroll
    for (int i = 0; i < 4; i++) af[i] = Ac[quad * 128 + wm * 64 + i * 16 + l15];
#pragma unroll
    for (int j = 0; j < 4; j++) bfr[j] = Bc[quad * 128 + wn * 64 + j * 16 + l15];
#pragma unroll
    for (int i = 0; i < 4; i++)
#pragma unroll
      for (int j = 0; j < 4; j++)
        acc[i][j] = __builtin_amdgcn_mfma_f32_16x16x32_bf16(af[i], bfr[j], acc[i][j], 0, 0, 0);
    cur = (cur == 2) ? 0 : cur + 1;
  }

  const int m0 = blockM + wm * 64 + quad * 4;
  const int n0 = blockN + wn * 64 + l15;
  if (MODE == 0) {
    u16* o0 = (u16*)o0v; u16* o1 = (u16*)o1v; u16* o2 = (u16*)o2v;
#pragma unroll
    for (int j = 0; j < 4; j++) {
      int n = n0 + j * 16;
      int sec = n >> 10, hh = (n >> 6) & 15, d = n & 63;
      u16* dst = (sec == 0) ? o0 : (sec == 1) ? o1 : o2;
#pragma unroll
      for (int i = 0; i < 4; i++)
#pragma unroll
        for (int r = 0; r < 4; r++) {
          int m = m0 + i * 16 + r;
          int b = m >> 11, t = m & 2047;
          dst[((size_t)((b * 16 + hh) * 2048 + t)) * 64 + d] = f2b(acc[i][j][r]);
        }
    }
  } else if (MODE == 1) {
    u16* o0 = (u16*)o0v;
#pragma unroll
    for (int j = 0; j < 4; j++) {
      int n = n0 + j * 16;
      float bv = bias[n];
#pragma unroll
      for (int i = 0; i < 4; i++)
#pragma unroll
        for (int r = 0; r < 4; r++) {
          int m = m0 + i * 16 + r;
          o0[(size_t)m * N + n] = f2b(acc[i][j][r] + bv);
        }
    }
  } else {
    float* o0 = (float*)o0v;
#pragma unroll
    for (int j = 0; j < 4; j++) {
      int n = n0 + j * 16;
      float bv = bias[n];
#pragma unroll
      for (int i = 0; i < 4; i++)
#pragma unroll
        for (int r = 0; r < 4; r++) {
          int m = m0 + i * 16 + r;
          float v = acc[i][j][r] + bv;
          o0[(size_t)m * N + n] = v > 0.f ? v : 0.f;
        }
    }
  }
}

// ---------------- MFMA causal flash attention, LDS-staged, balanced -----------
__global__ __launch_bounds__(256) void attn_mfma(
    const u16* __restrict__ Q, const u16* __restrict__ K,
    const u16* __restrict__ Vt, u16* __restrict__ out) {
  __shared__ __align__(16) u16 Kbuf[2][4096];
  __shared__ __align__(16) u16 Vbuf[2][4096];
  __shared__ __align__(16) u16 Plds[4][32][72];
  const int tid = threadIdx.x;
  const int wave = tid >> 6, lane = tid & 63;
  const int quad = lane >> 4, l15 = lane & 15;
  const int sx = l15 & 7;
  const int bh = blockIdx.y;
  const int u = blockIdx.x;
  const size_t qkb = (size_t)bh * CTX * 64;
  const size_t vb = (size_t)bh * 64 * CTX;

  const int ch0 = wave * 64 + lane;
  const int ch1 = 256 + ch0;
  const int r0 = ch0 >> 3, s0 = (ch0 & 7) ^ (r0 & 7);
  const int r1 = ch1 >> 3, s1 = (ch1 & 7) ^ (r1 & 7);
  const u16* kg0 = K + qkb + r0 * 64 + s0 * 8;
  const u16* kg1 = K + qkb + r1 * 64 + s1 * 8;
  const u16* vg0 = Vt + vb + (size_t)r0 * CTX + s0 * 8;
  const u16* vg1 = Vt + vb + (size_t)r1 * CTX + s1 * 8;

#pragma unroll 1
  for (int pass = 0; pass < 2; pass++) {
    const int j = pass ? (15 - u) : u;
    const int qbase = j * 128 + wave * 32;
    const int NST = 2 * j + 2;
    const int nstw = 2 * j + (wave >> 1) + 1;

    bf16x8 qf[2][2];
#pragma unroll
    for (int mt = 0; mt < 2; mt++)
#pragma unroll
      for (int kc = 0; kc < 2; kc++)
        qf[mt][kc] = *(const bf16x8*)(Q + qkb + (size_t)(qbase + mt * 16 + l15) * 64 + kc * 32 + quad * 8);

    floatx4 o[2][4];
#pragma unroll
    for (int mt = 0; mt < 2; mt++)
#pragma unroll
      for (int dt = 0; dt < 4; dt++) o[mt][dt] = (floatx4){0.f, 0.f, 0.f, 0.f};
    float mrow[2] = {-1e30f, -1e30f};
    float lrow[2] = {0.f, 0.f};

    __syncthreads();
    gl2lds16(kg0, &Kbuf[0][wave * 512]);
    gl2lds16(kg1, &Kbuf[0][2048 + wave * 512]);
    gl2lds16(vg0, &Vbuf[0][wave * 512]);
    gl2lds16(vg1, &Vbuf[0][2048 + wave * 512]);

#pragma unroll 1
    for (int st = 0; st < NST; st++) {
      __syncthreads();
      if (st + 1 < NST) {
        const int sb = (st + 1) * 64;
        const int b = (st + 1) & 1;
        gl2lds16(kg0 + sb * 64, &Kbuf[b][wave * 512]);
        gl2lds16(kg1 + sb * 64, &Kbuf[b][2048 + wave * 512]);
        gl2lds16(vg0 + sb, &Vbuf[b][wave * 512]);
        gl2lds16(vg1 + sb, &Vbuf[b][2048 + wave * 512]);
      }
      if (st >= nstw) continue;
      const int sbase = st * 64;
      const u16* kb = Kbuf[st & 1];
      const u16* vv = Vbuf[st & 1];

      floatx4 stf[2][4];
#pragma unroll
      for (int sc = 0; sc < 4; sc++) {
        const bf16x8* kr = (const bf16x8*)(kb + (sc * 16 + l15) * 64);
        bf16x8 k0 = kr[quad ^ sx];
        bf16x8 k1 = kr[(4 + quad) ^ sx];
#pragma unroll
        for (int mt = 0; mt < 2; mt++) {
          floatx4 z = (floatx4){0.f, 0.f, 0.f, 0.f};
          z = __builtin_amdgcn_mfma_f32_16x16x32_bf16(k0, qf[mt][0], z, 0, 0, 0);
          stf[mt][sc] = __builtin_amdgcn_mfma_f32_16x16x32_bf16(k1, qf[mt][1], z, 0, 0, 0);
        }
      }
      if (st == nstw - 1) {
#pragma unroll
        for (int mt = 0; mt < 2; mt++) {
          int qq = qbase + mt * 16 + l15;
#pragma unroll
          for (int sc = 0; sc < 4; sc++)
#pragma unroll
            for (int r = 0; r < 4; r++) {
              int s = sbase + sc * 16 + quad * 4 + r;
              if (s > qq) stf[mt][sc][r] = -1e30f;
            }
        }
      }
#pragma unroll
      for (int mt = 0; mt < 2; mt++) {
        floatx4 m4 = fmax4(fmax4(stf[mt][0], stf[mt][1]), fmax4(stf[mt][2], stf[mt][3]));
        float tm = fmaxf(fmaxf(m4[0], m4[1]), fmaxf(m4[2], m4[3]));
        tm = fmaxf(tm, __shfl_xor(tm, 16));
        tm = fmaxf(tm, __shfl_xor(tm, 32));
        float mnew = fmaxf(mrow[mt], tm);
        float alpha = exp2f((mrow[mt] - mnew) * C_SCALE);
        float mc = mnew * C_SCALE;
        mrow[mt] = mnew;
        float lsum = 0.f;
#pragma unroll
        for (int sc = 0; sc < 4; sc++) {
          floatx4 s4 = stf[mt][sc];
          float p0 = exp2f(s4[0] * C_SCALE - mc);
          float p1 = exp2f(s4[1] * C_SCALE - mc);
          float p2 = exp2f(s4[2] * C_SCALE - mc);
          float p3 = exp2f(s4[3] * C_SCALE - mc);
          lsum += (p0 + p1) + (p2 + p3);
          *(uint2*)&Plds[wave][mt * 16 + l15][sc * 16 + quad * 4] =
              make_uint2(pack2(p0, p1), pack2(p2, p3));
        }
        lrow[mt] = lrow[mt] * alpha + lsum;
#pragma unroll
        for (int dt = 0; dt < 4; dt++) o[mt][dt] *= alpha;
      }
      asm volatile("s_waitcnt lgkmcnt(0)" ::: "memory");
#pragma unroll
      for (int sc2 = 0; sc2 < 2; sc2++) {
        bf16x8 pf[2];
#pragma unroll
        for (int mt = 0; mt < 2; mt++)
          pf[mt] = *(const bf16x8*)&Plds[wave][mt * 16 + l15][sc2 * 32 + quad * 8];
#pragma unroll
        for (int dt = 0; dt < 4; dt++) {
          const bf16x8* vr = (const bf16x8*)(vv + (dt * 16 + l15) * 64);
          bf16x8 vf = vr[(sc2 * 4 + quad) ^ sx];
#pragma unroll
          for (int mt = 0; mt < 2; mt++)
            o[mt][dt] = __builtin_amdgcn_mfma_f32_16x16x32_bf16(vf, pf[mt], o[mt][dt], 0, 0, 0);
        }
      }
    }

#pragma unroll
    for (int mt = 0; mt < 2; mt++) {
      float l = lrow[mt];
      l += __shfl_xor(l, 16);
      l += __shfl_xor(l, 32);
      float inv = 1.0f / l;
      int row = (bh >> 4) * CTX + qbase + mt * 16 + l15;
      u16* orow = out + (size_t)row * DMODEL + (bh & 15) * 64;
#pragma unroll
      for (int dt = 0; dt < 4; dt++) {
        floatx4 v = o[mt][dt];
        *(u32*)(orow + dt * 16 + quad * 4) = pack2(v[0] * inv, v[1] * inv);
        *(u32*)(orow + dt * 16 + quad * 4 + 2) = pack2(v[2] * inv, v[3] * inv);
      }
    }
  }
}

extern "C" void kernel_launch(void* const* d_in, const int* in_sizes, int n_in,
                              void* d_out, int out_size, void* d_ws, size_t ws_size,
                              hipStream_t stream) {
  const float* x  = (const float*)d_in[0];
  const float* Wq = (const float*)d_in[1];
  const float* Wk = (const float*)d_in[2];
  const float* Wv = (const float*)d_in[3];
  const float* W1 = (const float*)d_in[4];
  const float* b1 = (const float*)d_in[5];
  const float* W2 = (const float*)d_in[6];
  const float* b2 = (const float*)d_in[7];
  float* out = (float*)d_out;

  u16* ws    = (u16*)d_ws;
  u16* W1t   = ws;                             // [4096][1024]
  u16* W2t   = W1t + (size_t)4096 * 1024;      // [1024][4096]
  u16* att   = W2t + (size_t)4096 * 1024;      // [B*T][1024]  (also v_tmp)
  u16* xb    = att + (size_t)MROWS * 1024;     // [B*T][1024]
  u16* Wqkvt = xb + (size_t)MROWS * 1024;      // [3072][1024]
  u16* q     = Wqkvt + (size_t)3072 * 1024;    // [B*H][T][64]
  u16* k     = q + (size_t)MROWS * 1024;       // [B*H][T][64]
  u16* vt    = k + (size_t)MROWS * 1024;       // [B*H][64][T]
  u16* v_tmp = att;                            // [B*H][T][64]
  u16* h     = xb;                             // [B*T][4096] overlaps xb..vt

  cvt_f32_bf16<<<MROWS * 1024 / 1024, 256, 0, stream>>>(x, xb);

  dim3 tb(32, 8);
  transpose_qkv<<<dim3(2, 32, 48), tb, 0, stream>>>(Wq, Wk, Wv, Wqkvt);
  transpose_f32_bf16<<<dim3(128, 32, 1), tb, 0, stream>>>(W1, W1t, 1024, 4096, 0, 0);
  transpose_f32_bf16<<<dim3(32, 128, 1), tb, 0, stream>>>(W2, W2t, 4096, 1024, 0, 0);

  // QKV projection: [8192][1024] x [3072][1024]^T -> q/k/v (coalesced scatter)
  gemm_bt<0><<<1536, 256, 0, stream>>>(xb, Wqkvt, nullptr, q, k, v_tmp, 3072, 1024, 3);
  // v [BH][T][64] -> vt [BH][64][T]
  transpose_v_bf16<<<dim3(2, 64, 64), tb, 0, stream>>>(v_tmp, vt);
  // MFMA causal flash attention -> att [B*T][1024]
  attn_mfma<<<dim3(8, 64), 256, 0, stream>>>(q, k, vt, att);
  // FFN1: att @ W1 + b1 -> h (bf16)
  gemm_bt<1><<<2048, 256, 0, stream>>>(att, W1t, b1, h, nullptr, nullptr, 4096, 1024, 4);
  // FFN2: relu(h @ W2 + b2) -> out (fp32)
  gemm_bt<2><<<512, 256, 0, stream>>>(h, W2t, b2, out, nullptr, nullptr, 1024, 4096, 1);
}